// Round 1
// baseline (215.075 us; speedup 1.0000x reference)
//
#include <hip/hip_runtime.h>
#include <math.h>

#define HID 2048
#define SEQ 16384

// ---------------------------------------------------------------------------
// k1: v[h] = sum_d hidden[d] * W[d*HID + h]
// grid: (HID/256, 32) ; block: 256
// Each block: columns h = bx*256..+255, rows d = by*64..+63.
// Coalesced W reads (consecutive lanes -> consecutive h), hidden[d] is a
// wave-uniform scalar load. One atomicAdd per thread at the end (32 adders
// per address, spread in time -> negligible contention).
// ---------------------------------------------------------------------------
__global__ __launch_bounds__(256) void compute_v_kernel(
    const float* __restrict__ hidden,
    const float* __restrict__ W,
    float* __restrict__ v)
{
    const int h  = blockIdx.x * 256 + threadIdx.x;
    const int d0 = blockIdx.y * 64;
    float partial = 0.0f;
#pragma unroll 8
    for (int i = 0; i < 64; ++i) {
        const int d = d0 + i;
        partial = fmaf(hidden[d], W[(size_t)d * HID + h], partial);
    }
    atomicAdd(&v[h], partial);
}

// ---------------------------------------------------------------------------
// k2: energies[s] = enc[s,:] . v
// One wave (64 lanes) per row s, 4 waves per block, grid = SEQ/4 blocks.
// float4 loads: 512 float4 per row = 64 lanes x 8 iters. v (8 KB) lives in
// L1/L2 after first touch. Shuffle-only reduction, lane 0 writes.
// ---------------------------------------------------------------------------
__global__ __launch_bounds__(256) void compute_energies_kernel(
    const float* __restrict__ enc,
    const float* __restrict__ v,
    float* __restrict__ energies)
{
    const int lane = threadIdx.x & 63;
    const int wave = threadIdx.x >> 6;
    const int s    = blockIdx.x * 4 + wave;

    const float4* __restrict__ row = (const float4*)(enc + (size_t)s * HID);
    const float4* __restrict__ v4  = (const float4*)v;

    float acc = 0.0f;
#pragma unroll
    for (int i = 0; i < 8; ++i) {
        const int idx = i * 64 + lane;      // 0..511
        const float4 a = row[idx];
        const float4 b = v4[idx];
        acc += a.x * b.x + a.y * b.y + a.z * b.z + a.w * b.w;
    }
#pragma unroll
    for (int off = 32; off > 0; off >>= 1)
        acc += __shfl_down(acc, off, 64);

    if (lane == 0) energies[s] = acc;
}

// ---------------------------------------------------------------------------
// k3: out = softmax(energies) over all 16384 elements. Single block of 1024
// threads, 16 elements per thread held in registers. Two-phase reduction
// (max, then sum of exp) through LDS. b . hidden is a constant shift ->
// cancelled by softmax, so it never appears.
// ---------------------------------------------------------------------------
__global__ __launch_bounds__(1024) void softmax_kernel(
    const float* __restrict__ energies,
    float* __restrict__ out)
{
    __shared__ float red[16];
    __shared__ float bcast;

    const int tid  = threadIdx.x;
    const int lane = tid & 63;
    const int wave = tid >> 6;

    const float4* __restrict__ e4 = (const float4*)energies;
    float4*       __restrict__ o4 = (float4*)out;

    float vals[16];
    float m = -INFINITY;
#pragma unroll
    for (int i = 0; i < 4; ++i) {
        const float4 a = e4[i * 1024 + tid];
        vals[i * 4 + 0] = a.x;
        vals[i * 4 + 1] = a.y;
        vals[i * 4 + 2] = a.z;
        vals[i * 4 + 3] = a.w;
        m = fmaxf(m, fmaxf(fmaxf(a.x, a.y), fmaxf(a.z, a.w)));
    }

    // block max
#pragma unroll
    for (int off = 32; off > 0; off >>= 1)
        m = fmaxf(m, __shfl_down(m, off, 64));
    if (lane == 0) red[wave] = m;
    __syncthreads();
    if (tid == 0) {
        float mm = red[0];
#pragma unroll
        for (int i = 1; i < 16; ++i) mm = fmaxf(mm, red[i]);
        bcast = mm;
    }
    __syncthreads();
    const float gmax = bcast;
    __syncthreads();               // ensure everyone read red[] / bcast before reuse

    // exp + block sum
    float lsum = 0.0f;
#pragma unroll
    for (int i = 0; i < 16; ++i) {
        vals[i] = __expf(vals[i] - gmax);
        lsum += vals[i];
    }
#pragma unroll
    for (int off = 32; off > 0; off >>= 1)
        lsum += __shfl_down(lsum, off, 64);
    if (lane == 0) red[wave] = lsum;
    __syncthreads();
    if (tid == 0) {
        float tot = red[0];
#pragma unroll
        for (int i = 1; i < 16; ++i) tot += red[i];
        bcast = 1.0f / tot;
    }
    __syncthreads();
    const float inv = bcast;

#pragma unroll
    for (int i = 0; i < 4; ++i) {
        float4 o;
        o.x = vals[i * 4 + 0] * inv;
        o.y = vals[i * 4 + 1] * inv;
        o.z = vals[i * 4 + 2] * inv;
        o.w = vals[i * 4 + 3] * inv;
        o4[i * 1024 + tid] = o;
    }
}

// ---------------------------------------------------------------------------
extern "C" void kernel_launch(void* const* d_in, const int* in_sizes, int n_in,
                              void* d_out, int out_size, void* d_ws, size_t ws_size,
                              hipStream_t stream)
{
    const float* hidden = (const float*)d_in[0];   // [1, 2048]
    const float* enc    = (const float*)d_in[1];   // [16384, 2048]
    const float* W      = (const float*)d_in[2];   // [2048, 2048]
    // d_in[3] = b : dropped — constant shift, cancelled by softmax.

    float* out      = (float*)d_out;               // [16384]
    float* v        = (float*)d_ws;                // 2048 floats
    float* energies = v + HID;                     // 16384 floats

    // ws is re-poisoned to 0xAA before every timed call -> zero the atomic
    // accumulator each launch (memset node is graph-capture safe).
    hipMemsetAsync(v, 0, HID * sizeof(float), stream);

    compute_v_kernel<<<dim3(HID / 256, 32), 256, 0, stream>>>(hidden, W, v);
    compute_energies_kernel<<<SEQ / 4, 256, 0, stream>>>(enc, v, energies);
    softmax_kernel<<<1, 1024, 0, stream>>>(energies, out);
}

// Round 2
// 212.333 us; speedup vs baseline: 1.0129x; 1.0129x over previous
//
#include <hip/hip_runtime.h>
#include <math.h>

#define HID 2048
#define SEQ 16384

// ---------------------------------------------------------------------------
// k1: v[h] = sum_d hidden[d] * W[d*HID + h]
// grid: (HID/256, 32) ; block: 256
// Each block: columns h = bx*256..+255, rows d = by*64..+63.
// Coalesced W reads, hidden[d] is a wave-uniform scalar load. One atomicAdd
// per thread (64 contenders per address, spread in time).
// ---------------------------------------------------------------------------
__global__ __launch_bounds__(256) void compute_v_kernel(
    const float* __restrict__ hidden,
    const float* __restrict__ W,
    float* __restrict__ v)
{
    const int h  = blockIdx.x * 256 + threadIdx.x;
    const int d0 = blockIdx.y * 64;
    float partial = 0.0f;
#pragma unroll 8
    for (int i = 0; i < 64; ++i) {
        const int d = d0 + i;
        partial = fmaf(hidden[d], W[(size_t)d * HID + h], partial);
    }
    atomicAdd(&v[h], partial);
}

// ---------------------------------------------------------------------------
// k2: energies[s] = enc[s,:] . v
// Each wave preloads its v-fragment (8 float4 = the full 2048 across 64
// lanes) into registers ONCE, then processes R=4 rows — halves the load
// instructions vs reloading v per row. Block = 4 waves -> 16 rows/block,
// grid = 1024 blocks (4 blocks/CU, 16 waves/CU).
// ---------------------------------------------------------------------------
#define ROWS_PER_WAVE 4

__global__ __launch_bounds__(256) void compute_energies_kernel(
    const float* __restrict__ enc,
    const float* __restrict__ v,
    float* __restrict__ energies)
{
    const int lane = threadIdx.x & 63;
    const int wave = threadIdx.x >> 6;
    const int row0 = blockIdx.x * (4 * ROWS_PER_WAVE) + wave * ROWS_PER_WAVE;

    const float4* __restrict__ v4 = (const float4*)v;

    float4 vr[8];
#pragma unroll
    for (int j = 0; j < 8; ++j)
        vr[j] = v4[j * 64 + lane];          // wave collectively holds all of v

#pragma unroll
    for (int r = 0; r < ROWS_PER_WAVE; ++r) {
        const int s = row0 + r;
        const float4* __restrict__ row = (const float4*)(enc + (size_t)s * HID);

        float acc = 0.0f;
#pragma unroll
        for (int j = 0; j < 8; ++j) {
            const float4 a = row[j * 64 + lane];
            acc = fmaf(a.x, vr[j].x, acc);
            acc = fmaf(a.y, vr[j].y, acc);
            acc = fmaf(a.z, vr[j].z, acc);
            acc = fmaf(a.w, vr[j].w, acc);
        }
#pragma unroll
        for (int off = 32; off > 0; off >>= 1)
            acc += __shfl_down(acc, off, 64);

        if (lane == 0) energies[s] = acc;
    }
}

// ---------------------------------------------------------------------------
// k3: out = softmax(energies), single 1024-thread block, 16 elems/thread in
// registers, two-phase (max, sum) LDS reduction. b.hidden is a constant
// shift cancelled by softmax -> b never used.
// ---------------------------------------------------------------------------
__global__ __launch_bounds__(1024) void softmax_kernel(
    const float* __restrict__ energies,
    float* __restrict__ out)
{
    __shared__ float red[16];
    __shared__ float bcast;

    const int tid  = threadIdx.x;
    const int lane = tid & 63;
    const int wave = tid >> 6;

    const float4* __restrict__ e4 = (const float4*)energies;
    float4*       __restrict__ o4 = (float4*)out;

    float vals[16];
    float m = -INFINITY;
#pragma unroll
    for (int i = 0; i < 4; ++i) {
        const float4 a = e4[i * 1024 + tid];
        vals[i * 4 + 0] = a.x;
        vals[i * 4 + 1] = a.y;
        vals[i * 4 + 2] = a.z;
        vals[i * 4 + 3] = a.w;
        m = fmaxf(m, fmaxf(fmaxf(a.x, a.y), fmaxf(a.z, a.w)));
    }

#pragma unroll
    for (int off = 32; off > 0; off >>= 1)
        m = fmaxf(m, __shfl_down(m, off, 64));
    if (lane == 0) red[wave] = m;
    __syncthreads();
    if (tid == 0) {
        float mm = red[0];
#pragma unroll
        for (int i = 1; i < 16; ++i) mm = fmaxf(mm, red[i]);
        bcast = mm;
    }
    __syncthreads();
    const float gmax = bcast;
    __syncthreads();

    float lsum = 0.0f;
#pragma unroll
    for (int i = 0; i < 16; ++i) {
        vals[i] = __expf(vals[i] - gmax);
        lsum += vals[i];
    }
#pragma unroll
    for (int off = 32; off > 0; off >>= 1)
        lsum += __shfl_down(lsum, off, 64);
    if (lane == 0) red[wave] = lsum;
    __syncthreads();
    if (tid == 0) {
        float tot = red[0];
#pragma unroll
        for (int i = 1; i < 16; ++i) tot += red[i];
        bcast = 1.0f / tot;
    }
    __syncthreads();
    const float inv = bcast;

#pragma unroll
    for (int i = 0; i < 4; ++i) {
        float4 o;
        o.x = vals[i * 4 + 0] * inv;
        o.y = vals[i * 4 + 1] * inv;
        o.z = vals[i * 4 + 2] * inv;
        o.w = vals[i * 4 + 3] * inv;
        o4[i * 1024 + tid] = o;
    }
}

// ---------------------------------------------------------------------------
extern "C" void kernel_launch(void* const* d_in, const int* in_sizes, int n_in,
                              void* d_out, int out_size, void* d_ws, size_t ws_size,
                              hipStream_t stream)
{
    const float* hidden = (const float*)d_in[0];   // [1, 2048]
    const float* enc    = (const float*)d_in[1];   // [16384, 2048]
    const float* W      = (const float*)d_in[2];   // [2048, 2048]
    // d_in[3] = b : constant shift, cancelled by softmax.

    float* out      = (float*)d_out;               // [16384]
    float* v        = (float*)d_ws;                // 2048 floats
    float* energies = v + HID;                     // 16384 floats

    // ws is re-poisoned to 0xAA before every call -> zero the accumulator.
    hipMemsetAsync(v, 0, HID * sizeof(float), stream);

    compute_v_kernel<<<dim3(HID / 256, 32), 256, 0, stream>>>(hidden, W, v);
    compute_energies_kernel<<<SEQ / (4 * ROWS_PER_WAVE), 256, 0, stream>>>(enc, v, energies);
    softmax_kernel<<<1, 1024, 0, stream>>>(energies, out);
}